// Round 8
// baseline (684.394 us; speedup 1.0000x reference)
//
#include <hip/hip_runtime.h>

#define N_NODES 100000
#define N_EDGES 1000000
#define N_GRAPHS 128
#define IN_DIM 32
#define HID 64
#define LAT 32
#define N_LAYERS 3

#define MPAD 68  // padded LDS row stride (floats), 16B-aligned rows
#define NB_SUM ((N_NODES + 255) / 256)  // 391 scan blocks

// bf16 <-> fp32 helpers (storage-only bf16; all math fp32)
__device__ __forceinline__ float bf2f(unsigned short u) {
    return __uint_as_float(((unsigned int)u) << 16);
}
__device__ __forceinline__ unsigned short f2bf(float f) {
    unsigned int x = __float_as_uint(f);
    x += 0x7fffu + ((x >> 16) & 1u);  // round-to-nearest-even
    return (unsigned short)(x >> 16);
}

// ---------------- input projection: h = bf16(x @ w_in + b_in) --------------
// also zeroes the CSR `counts` array (folds a memset dispatch)
__global__ __launch_bounds__(256) void proj_kernel(
    const float* __restrict__ x, const float* __restrict__ w_in,
    const float* __restrict__ b_in, unsigned short* __restrict__ h,
    int* __restrict__ counts) {
    __shared__ float ws[IN_DIM * HID];   // 8 KB
    __shared__ float xs[4 * IN_DIM];
    int tid = threadIdx.x;
    int gtid = blockIdx.x * 256 + tid;
    if (gtid < N_NODES) counts[gtid] = 0;
    for (int i = tid; i < IN_DIM * HID / 4; i += 256)
        ((float4*)ws)[i] = ((const float4*)w_in)[i];
    if (tid < 32) {
        int r = tid >> 3, c4 = tid & 7;
        int nn = blockIdx.x * 4 + r;
        float4 v = make_float4(0.f, 0.f, 0.f, 0.f);
        if (nn < N_NODES) v = ((const float4*)(x + (size_t)nn * IN_DIM))[c4];
        ((float4*)xs)[tid] = v;
    }
    __syncthreads();
    int w = tid >> 6, j = tid & 63;
    int n = blockIdx.x * 4 + w;
    if (n >= N_NODES) return;
    float acc = b_in[j];
#pragma unroll
    for (int k = 0; k < IN_DIM; k += 4) {
        float4 xv = *(const float4*)&xs[w * IN_DIM + k];
        acc += xv.x * ws[(k + 0) * HID + j];
        acc += xv.y * ws[(k + 1) * HID + j];
        acc += xv.z * ws[(k + 2) * HID + j];
        acc += xv.w * ws[(k + 3) * HID + j];
    }
    h[(size_t)n * HID + j] = f2bf(acc);
}

// ---------------- CSR build ----------------
// also zeroes `pooled` (folds a memset dispatch; pool runs much later)
__global__ __launch_bounds__(256) void hist_kernel(const int* __restrict__ ei,
                                                   int* __restrict__ counts,
                                                   float* __restrict__ pooled) {
    int e = blockIdx.x * 256 + threadIdx.x;
    if (e < N_GRAPHS * HID) pooled[e] = 0.f;
    if (e < N_EDGES) atomicAdd(&counts[ei[N_EDGES + e]], 1);
}

__global__ __launch_bounds__(256) void block_sum_kernel(
    const int* __restrict__ counts, int* __restrict__ bsums) {
    __shared__ int sd[4];
    int i = blockIdx.x * 256 + threadIdx.x;
    int v = (i < N_NODES) ? counts[i] : 0;
#pragma unroll
    for (int off = 32; off >= 1; off >>= 1) v += __shfl_down(v, off);
    int lane = threadIdx.x & 63, w = threadIdx.x >> 6;
    if (lane == 0) sd[w] = v;
    __syncthreads();
    if (threadIdx.x == 0) bsums[blockIdx.x] = sd[0] + sd[1] + sd[2] + sd[3];
}

__global__ __launch_bounds__(256) void scan_bsums_kernel(
    const int* __restrict__ bsums, int* __restrict__ bofs, int nb) {
    __shared__ int tmp[256];
    __shared__ int carry;
    int tid = threadIdx.x;
    if (tid == 0) carry = 0;
    __syncthreads();
    for (int base = 0; base < nb; base += 256) {
        int v = (base + tid < nb) ? bsums[base + tid] : 0;
        tmp[tid] = v;
        __syncthreads();
        for (int off = 1; off < 256; off <<= 1) {
            int t = (tid >= off) ? tmp[tid - off] : 0;
            __syncthreads();
            tmp[tid] += t;
            __syncthreads();
        }
        if (base + tid < nb) bofs[base + tid] = carry + tmp[tid] - v;
        __syncthreads();
        if (tid == 255) carry += tmp[255];
        __syncthreads();
    }
}

__global__ __launch_bounds__(256) void offsets_kernel(
    const int* __restrict__ counts, const int* __restrict__ bofs,
    int* __restrict__ offsets, int* __restrict__ cursor) {
    __shared__ int tmp[256];
    int tid = threadIdx.x;
    int i = blockIdx.x * 256 + tid;
    int v = (i < N_NODES) ? counts[i] : 0;
    tmp[tid] = v;
    __syncthreads();
    for (int off = 1; off < 256; off <<= 1) {
        int t = (tid >= off) ? tmp[tid - off] : 0;
        __syncthreads();
        tmp[tid] += t;
        __syncthreads();
    }
    int excl = tmp[tid] - v + bofs[blockIdx.x];
    if (i < N_NODES) {
        offsets[i] = excl;
        cursor[i] = excl;
        if (i == N_NODES - 1) offsets[N_NODES] = excl + v;
    }
}

// plain store (R5 lesson: nontemporal scatter bypasses L2 write-combining -> ~2x slower)
__global__ __launch_bounds__(256) void fill_kernel(const int* __restrict__ ei,
                                                   int* __restrict__ cursor,
                                                   int* __restrict__ srcs) {
    int e = blockIdx.x * 256 + threadIdx.x;
    if (e < N_EDGES) {
        int d = ei[N_EDGES + e];
        int p = atomicAdd(&cursor[d], 1);
        srcs[p] = ei[e];
    }
}

// ---------------- fused layer: gather + GIN MLP (bf16 h storage) -----------
// block = 64 nodes, 512 threads (8 waves). Gather processes TWO rows per
// wave concurrently (R7 lesson: per-row degree ~10 exposes too few
// outstanding loads; row-serial = 8 sequential RTTs/wave). Quarter-wave q
// = edge slot; lane loads uint2 = 4 bf16 feats. Single 16 KB weight
// buffer: w1 staged, w2 preloaded to regs and swapped in post-GEMM1.
__global__ __launch_bounds__(512) void layer_kernel(
    const unsigned short* __restrict__ h_in, unsigned short* __restrict__ h_out,
    const int* __restrict__ offsets, const int* __restrict__ srcs,
    const float* __restrict__ w1, const float* __restrict__ b1,
    const float* __restrict__ w2, const float* __restrict__ b2) {
    __shared__ float ws[HID * HID];    // 16 KB, holds w1 then w2
    __shared__ float ms[64 * MPAD];    // 17.4 KB, m then t
    int tid = threadIdx.x;
    int row0 = blockIdx.x * 64;

    // stage w1 -> LDS (conflict-free [tid],[tid+512] — R7's [2t],[2t+1] hit
    // 400k bank conflicts); preload w2 -> regs
    float4 w1a = ((const float4*)w1)[tid];
    float4 w1b = ((const float4*)w1)[tid + 512];
    float4 w2a = ((const float4*)w2)[tid];
    float4 w2b = ((const float4*)w2)[tid + 512];
    ((float4*)ws)[tid] = w1a;
    ((float4*)ws)[tid + 512] = w1b;

    int w = tid >> 6, j = tid & 63;
    int q = j >> 4;          // edge slot 0..3
    int fo = (j & 15) << 2;  // feature offset (4 feats per lane)

#define UNPACK_ADD(A, V)                               \
    do {                                               \
        (A).x += __uint_as_float((V).x << 16);         \
        (A).y += __uint_as_float((V).x & 0xffff0000u); \
        (A).z += __uint_as_float((V).y << 16);         \
        (A).w += __uint_as_float((V).y & 0xffff0000u); \
    } while (0)

// process up to 64 edges (wave-uniform mS) from broadcast reg myS
#define GATHER_SLOTS(myS, mS, A0, A1, i2)                               \
    if (i2 < mS) {                                                      \
        int ia = i2 + q, ib = i2 + 4 + q;                               \
        if (ia < mS) {                                                  \
            int s = __shfl(myS, ia);                                    \
            uint2 v = *(const uint2*)(h_in + (size_t)s * HID + fo);     \
            UNPACK_ADD(A0, v);                                          \
        }                                                               \
        if (ib < mS) {                                                  \
            int s = __shfl(myS, ib);                                    \
            uint2 v = *(const uint2*)(h_in + (size_t)s * HID + fo);     \
            UNPACK_ADD(A1, v);                                          \
        }                                                               \
    }

    for (int rr = 0; rr < 8; rr += 2) {
        int rA = w * 8 + rr, rB = rA + 1;
        int nA = row0 + rA, nB = row0 + rB;
        float4 aA0 = make_float4(0.f, 0.f, 0.f, 0.f), aA1 = aA0;
        float4 aB0 = aA0, aB1 = aA0;
        int begA = 0, endA = 0, begB = 0, endB = 0;
        if (nA < N_NODES) { begA = offsets[nA]; endA = offsets[nA + 1]; }
        if (nB < N_NODES) { begB = offsets[nB]; endB = offsets[nB + 1]; }
        int myA = (begA + j < endA) ? srcs[begA + j] : 0;
        int myB = (begB + j < endB) ? srcs[begB + j] : 0;
        int mA = min(64, endA - begA), mB = min(64, endB - begB);
        // interleaved first chunk of both rows: ~2x loads in flight
#pragma unroll
        for (int i2 = 0; i2 < 64; i2 += 8) {
            GATHER_SLOTS(myA, mA, aA0, aA1, i2)
            GATHER_SLOTS(myB, mB, aB0, aB1, i2)
        }
        // rare overflow chunks (degree > 64)
        for (int c = begA + 64; c < endA; c += 64) {
            int myS = (c + j < endA) ? srcs[c + j] : 0;
            int m = min(64, endA - c);
#pragma unroll
            for (int i2 = 0; i2 < 64; i2 += 8) GATHER_SLOTS(myS, m, aA0, aA1, i2)
        }
        for (int c = begB + 64; c < endB; c += 64) {
            int myS = (c + j < endB) ? srcs[c + j] : 0;
            int m = min(64, endB - c);
#pragma unroll
            for (int i2 = 0; i2 < 64; i2 += 8) GATHER_SLOTS(myS, m, aB0, aB1, i2)
        }
        // self term (m = agg + h, eps=0): only q==0 so it's counted once
        if (q == 0) {
            if (nA < N_NODES) {
                uint2 v = *(const uint2*)(h_in + (size_t)nA * HID + fo);
                UNPACK_ADD(aA0, v);
            }
            if (nB < N_NODES) {
                uint2 v = *(const uint2*)(h_in + (size_t)nB * HID + fo);
                UNPACK_ADD(aB0, v);
            }
        }
        // cross-quarter reduce + LDS write (invalid rows write zeros)
        aA0.x += aA1.x; aA0.y += aA1.y; aA0.z += aA1.z; aA0.w += aA1.w;
        aB0.x += aB1.x; aB0.y += aB1.y; aB0.z += aB1.z; aB0.w += aB1.w;
        aA0.x += __shfl_xor(aA0.x, 16); aA0.y += __shfl_xor(aA0.y, 16);
        aA0.z += __shfl_xor(aA0.z, 16); aA0.w += __shfl_xor(aA0.w, 16);
        aB0.x += __shfl_xor(aB0.x, 16); aB0.y += __shfl_xor(aB0.y, 16);
        aB0.z += __shfl_xor(aB0.z, 16); aB0.w += __shfl_xor(aB0.w, 16);
        aA0.x += __shfl_xor(aA0.x, 32); aA0.y += __shfl_xor(aA0.y, 32);
        aA0.z += __shfl_xor(aA0.z, 32); aA0.w += __shfl_xor(aA0.w, 32);
        aB0.x += __shfl_xor(aB0.x, 32); aB0.y += __shfl_xor(aB0.y, 32);
        aB0.z += __shfl_xor(aB0.z, 32); aB0.w += __shfl_xor(aB0.w, 32);
        if (q == 0) {
            *(float4*)&ms[rA * MPAD + fo] = aA0;
            *(float4*)&ms[rB * MPAD + fo] = aB0;
        }
    }
#undef GATHER_SLOTS
#undef UNPACK_ADD
    __syncthreads();  // #1: ms(m) and ws(w1) visible

    // ---- GEMM phase: ty 0..31 (2 rows), tx 0..15 (4 cols) ----
    int ty = tid >> 4, tx = tid & 15;
    int r0 = ty * 2, c0 = tx * 4;

    float4 a0, a1;
#define GEMM_LDS()                                                            \
    do {                                                                      \
        a0 = make_float4(0.f, 0.f, 0.f, 0.f); a1 = a0;                        \
        _Pragma("unroll 4")                                                   \
        for (int k0 = 0; k0 < HID; k0 += 4) {                                 \
            float4 m0 = *(const float4*)&ms[(r0 + 0) * MPAD + k0];            \
            float4 m1 = *(const float4*)&ms[(r0 + 1) * MPAD + k0];            \
            float4 w0 = *(const float4*)&ws[(k0 + 0) * HID + c0];             \
            float4 w1v = *(const float4*)&ws[(k0 + 1) * HID + c0];            \
            float4 w2v = *(const float4*)&ws[(k0 + 2) * HID + c0];            \
            float4 w3v = *(const float4*)&ws[(k0 + 3) * HID + c0];            \
            a0.x += m0.x * w0.x + m0.y * w1v.x + m0.z * w2v.x + m0.w * w3v.x; \
            a0.y += m0.x * w0.y + m0.y * w1v.y + m0.z * w2v.y + m0.w * w3v.y; \
            a0.z += m0.x * w0.z + m0.y * w1v.z + m0.z * w2v.z + m0.w * w3v.z; \
            a0.w += m0.x * w0.w + m0.y * w1v.w + m0.z * w2v.w + m0.w * w3v.w; \
            a1.x += m1.x * w0.x + m1.y * w1v.x + m1.z * w2v.x + m1.w * w3v.x; \
            a1.y += m1.x * w0.y + m1.y * w1v.y + m1.z * w2v.y + m1.w * w3v.y; \
            a1.z += m1.x * w0.z + m1.y * w1v.z + m1.z * w2v.z + m1.w * w3v.z; \
            a1.w += m1.x * w0.w + m1.y * w1v.w + m1.z * w2v.w + m1.w * w3v.w; \
        }                                                                     \
    } while (0)

    GEMM_LDS();  // GEMM1 (ws = w1)

    float4 bv1 = *(const float4*)&b1[c0];
    float4 t0 = make_float4(fmaxf(a0.x + bv1.x, 0.f), fmaxf(a0.y + bv1.y, 0.f),
                            fmaxf(a0.z + bv1.z, 0.f), fmaxf(a0.w + bv1.w, 0.f));
    float4 t1 = make_float4(fmaxf(a1.x + bv1.x, 0.f), fmaxf(a1.y + bv1.y, 0.f),
                            fmaxf(a1.z + bv1.z, 0.f), fmaxf(a1.w + bv1.w, 0.f));

    __syncthreads();  // #2: all GEMM1 reads of ms AND ws complete
    *(float4*)&ms[(r0 + 0) * MPAD + c0] = t0;
    *(float4*)&ms[(r0 + 1) * MPAD + c0] = t1;
    ((float4*)ws)[tid] = w2a;       // overwrite ws with w2
    ((float4*)ws)[tid + 512] = w2b;
    __syncthreads();  // #3: ms(t) and ws(w2) visible

    GEMM_LDS();  // GEMM2 (ws = w2)

    float4 bv2 = *(const float4*)&b2[c0];
#pragma unroll
    for (int i = 0; i < 2; i++) {
        int n = row0 + r0 + i;
        if (n < N_NODES) {
            float4 av = (i == 0) ? a0 : a1;
            const unsigned short* hp = h_in + (size_t)n * HID + c0;
            float o0 = fmaxf(av.x + bv2.x, 0.f) + bf2f(hp[0]);
            float o1 = fmaxf(av.y + bv2.y, 0.f) + bf2f(hp[1]);
            float o2 = fmaxf(av.z + bv2.z, 0.f) + bf2f(hp[2]);
            float o3 = fmaxf(av.w + bv2.w, 0.f) + bf2f(hp[3]);
            uint2 pk;
            pk.x = (unsigned int)f2bf(o0) | ((unsigned int)f2bf(o1) << 16);
            pk.y = (unsigned int)f2bf(o2) | ((unsigned int)f2bf(o3) << 16);
            *(uint2*)(h_out + (size_t)n * HID + c0) = pk;
        }
    }
#undef GEMM_LDS
}

// ---------------- global add pool (bf16 h) ----------------
__global__ __launch_bounds__(256) void pool_kernel(
    const unsigned short* __restrict__ h, const int* __restrict__ batch,
    float* __restrict__ pooled) {
    int tid = threadIdx.x;
    int w = tid >> 6, j = tid & 63;
    int n0 = blockIdx.x * 256 + w * 64;
    if (n0 >= N_NODES) return;
    int nend = min(n0 + 64, N_NODES);
    float acc = 0.f;
    int cur = batch[n0];
    for (int n = n0; n < nend; n++) {
        int b = batch[n];
        if (b != cur) {
            atomicAdd(&pooled[cur * HID + j], acc);
            acc = 0.f;
            cur = b;
        }
        acc += bf2f(h[(size_t)n * HID + j]);
    }
    atomicAdd(&pooled[cur * HID + j], acc);
}

// ---------------- final FC ----------------
__global__ __launch_bounds__(256) void final_kernel(
    const float* __restrict__ pooled, const float* __restrict__ w_fc,
    const float* __restrict__ b_fc, float* __restrict__ out) {
    int gid = blockIdx.x * 256 + threadIdx.x;
    if (gid >= N_GRAPHS * LAT) return;
    int g = gid >> 5, j = gid & 31;
    float acc = b_fc[j];
#pragma unroll
    for (int k = 0; k < HID; k++)
        acc += pooled[g * HID + k] * w_fc[k * LAT + j];
    out[gid] = acc;
}

extern "C" void kernel_launch(void* const* d_in, const int* in_sizes, int n_in,
                              void* d_out, int out_size, void* d_ws,
                              size_t ws_size, hipStream_t stream) {
    const float* x     = (const float*)d_in[0];
    const int*   ei    = (const int*)d_in[1];
    const int*   batch = (const int*)d_in[2];
    const float* w_in  = (const float*)d_in[3];
    const float* b_in  = (const float*)d_in[4];
    const float* w1    = (const float*)d_in[5];
    const float* b1    = (const float*)d_in[6];
    const float* w2    = (const float*)d_in[7];
    const float* b2    = (const float*)d_in[8];
    const float* w_fc  = (const float*)d_in[9];
    const float* b_fc  = (const float*)d_in[10];
    float* out = (float*)d_out;

    // persistent: h0 | h1 (bf16, 12.8 MB each) | pooled | offsets | srcs (~30 MB)
    unsigned short* h0 = (unsigned short*)d_ws;
    unsigned short* h1 = h0 + (size_t)N_NODES * HID;
    float* pooled  = (float*)(h1 + (size_t)N_NODES * HID);
    int*   offsets = (int*)(pooled + N_GRAPHS * HID);   // N_NODES+1
    int*   srcs    = offsets + (N_NODES + 2);           // N_EDGES
    // CSR build scratch overlaid into h1 (dead before layer 0 writes h1)
    int* counts = (int*)h1;             // N_NODES
    int* cursor = counts + N_NODES;     // N_NODES
    int* bsums  = cursor + N_NODES;     // NB_SUM
    int* bofs   = bsums + (NB_SUM + 1); // NB_SUM

    proj_kernel<<<(N_NODES + 3) / 4, 256, 0, stream>>>(x, w_in, b_in, h0, counts);

    // CSR build (once; edges constant across layers)
    hist_kernel<<<(N_EDGES + 255) / 256, 256, 0, stream>>>(ei, counts, pooled);
    block_sum_kernel<<<NB_SUM, 256, 0, stream>>>(counts, bsums);
    scan_bsums_kernel<<<1, 256, 0, stream>>>(bsums, bofs, NB_SUM);
    offsets_kernel<<<NB_SUM, 256, 0, stream>>>(counts, bofs, offsets, cursor);
    fill_kernel<<<(N_EDGES + 255) / 256, 256, 0, stream>>>(ei, cursor, srcs);

    // fused layers, h double-buffered: h0->h1->h0->h1
    const unsigned short* hin = h0;
    unsigned short* hout = h1;
    for (int i = 0; i < N_LAYERS; i++) {
        layer_kernel<<<(N_NODES + 63) / 64, 512, 0, stream>>>(
            hin, hout, offsets, srcs,
            w1 + (size_t)i * HID * HID, b1 + (size_t)i * HID,
            w2 + (size_t)i * HID * HID, b2 + (size_t)i * HID);
        const unsigned short* tmp = hout;
        hout = (unsigned short*)hin;
        hin = tmp;
    }

    pool_kernel<<<(N_NODES + 255) / 256, 256, 0, stream>>>(hin, batch, pooled);
    final_kernel<<<(N_GRAPHS * LAT + 255) / 256, 256, 0, stream>>>(
        pooled, w_fc, b_fc, out);
}